// Round 15
// baseline (753.056 us; speedup 1.0000x reference)
//
#include <hip/hip_runtime.h>
#include <hip/hip_bf16.h>
#include <math.h>

// ---------------------------------------------------------------------------
// Problem constants
// ---------------------------------------------------------------------------
#define NNODES 2048
#define NEDG   8192
#define E2     16384
#define NGRAPH 8
#define HSTR   152   // h row stride (max hidden dim)

static const int LD_DIN[4]  = {32,152,152,152};
static const int LD_DOUT[4] = {152,152,152,32};
static const int LD_WN[4]   = {1408,4320,4320,1408};
static const int LD_WNP[4]  = {1408,4352,4352,1408};   // padded to 128
static const int LD_NCH[4]  = {88,88,88,32};
static const int LD_RES[4]  = {32,152,152,152};
#define WNP_MAX 4352
#define WNP_TOT (1408+4352+4352+1408)   // 11520

// table sizes (element counts per layer)
#define SLOT_MAX    1088   // u32 per layer (zc <= 1072)
#define CELL_N      20     // u32 per layer (nc <= 15)
#define SEG_S_N     164    // ints per layer (Dout+1 <= 153)
#define SEG_ENT_MAX 1024   // u32 per layer (<=720 used)

typedef short bf16x8 __attribute__((ext_vector_type(8)));
typedef float f32x4  __attribute__((ext_vector_type(4)));

// ---------------------------------------------------------------------------
// Compile-time CG table (constexpr port of reference _su2_cg / _q / _real_cg)
// ---------------------------------------------------------------------------
constexpr double cfact(int n){ double r=1.0; for(int i=2;i<=n;i++) r*=(double)i; return r; }
constexpr double csqrt(double x){
  if(x<=0.0) return 0.0;
  double g = x>1.0? x:1.0;
  for(int i=0;i<64;i++) g=0.5*(g+x/g);
  return g;
}
constexpr double csu2cg(int j1,int j2,int j3,int m1,int m2,int m3){
  if(m1+m2!=m3) return 0.0;
  double pref = csqrt((double)(2*j3+1)*cfact(j3+j1-j2)*cfact(j3-j1+j2)*cfact(j1+j2-j3)/cfact(j1+j2+j3+1));
  pref *= csqrt(cfact(j3+m3)*cfact(j3-m3)*cfact(j1-m1)*cfact(j1+m1)*cfact(j2-m2)*cfact(j2+m2));
  double s=0.0;
  for(int k=0;k<=j1+j2-j3;k++){
    if(j1-m1-k<0||j2+m2-k<0||j3-j2+m1+k<0||j3-j1-m2+k<0) continue;
    double t=1.0/(cfact(k)*cfact(j1+j2-j3-k)*cfact(j1-m1-k)*cfact(j2+m2-k)*cfact(j3-j2+m1+k)*cfact(j3-j1-m2+k));
    s += (k&1)? -t : t;
  }
  return pref*s;
}
struct QM { double r[25]; double i[25]; };
constexpr QM cqmat(int l){
  QM q{};
  const double inv2=0.7071067811865476;
  for(int m=-l;m<0;m++){
    int am=-m;
    q.r[(l+m)*5+(l+am)] = inv2;
    q.i[(l+m)*5+(l-am)] = -inv2;
  }
  q.r[l*5+l]=1.0;
  for(int m=1;m<=l;m++){
    double sgn=(m&1)? -1.0:1.0;
    q.r[(l+m)*5+(l+m)] = sgn*inv2;
    q.i[(l+m)*5+(l-m)] = sgn*inv2;
  }
  for(int rep=0;rep<l;rep++){   // multiply by (-i): (a+bi)*(-i) = b - a i
    for(int t=0;t<25;t++){ double a=q.r[t], b=q.i[t]; q.r[t]=b; q.i[t]=-a; }
  }
  return q;
}
struct CGCell { float v[125]; };
constexpr CGCell mkcell(int l1,int l2,int l3){
  CGCell out{};
  int lo = l1>l2? l1-l2 : l2-l1;
  if(l3<lo || l3>l1+l2) return out;
  QM q1=cqmat(l1), q2=cqmat(l2), q3=cqmat(l3);
  int n1=2*l1+1,n2=2*l2+1,n3=2*l3+1;
  double C[125]={};
  for(int a=0;a<n1;a++)for(int b=0;b<n2;b++)for(int c=0;c<n3;c++)
    C[a*25+b*5+c]=csu2cg(l1,l2,l3,a-l1,b-l2,c-l3);
  double wr[125]={}, wi[125]={};
  for(int i=0;i<n1;i++)for(int j=0;j<n2;j++)for(int k=0;k<n3;k++){
    double ar=0.0, ai=0.0;
    for(int a=0;a<n1;a++)for(int b=0;b<n2;b++){
      double p1r=q1.r[a*5+i], p1i=q1.i[a*5+i];
      double p2r=q2.r[b*5+j], p2i=q2.i[b*5+j];
      double pr=p1r*p2r-p1i*p2i, pi=p1r*p2i+p1i*p2r;
      for(int c=0;c<n3;c++){
        double cv=C[a*25+b*5+c]; if(cv==0.0) continue;
        double p3r=q3.r[c*5+k], p3i=-q3.i[c*5+k];   // conj
        ar += (pr*p3r-pi*p3i)*cv;
        ai += (pr*p3i+pi*p3r)*cv;
      }
    }
    wr[i*25+j*5+k]=ar; wi[i*25+j*5+k]=ai;
  }
  double sr=0.0, si=0.0;
  for(int t=0;t<125;t++){ sr+=wr[t]*wr[t]; si+=wi[t]*wi[t]; }
  double nr=csqrt(sr), ni=csqrt(si);
  bool use_re = nr>=ni;
  double nn = use_re? nr:ni;
  double inv = (nn>1e-300)? 1.0/nn : 0.0;
  for(int t=0;t<125;t++) out.v[t]=(float)((use_re? wr[t]:wi[t])*inv);
  return out;
}
constexpr CGCell CGc0 =mkcell(0,0,0), CGc1 =mkcell(0,0,1), CGc2 =mkcell(0,0,2);
constexpr CGCell CGc3 =mkcell(0,1,0), CGc4 =mkcell(0,1,1), CGc5 =mkcell(0,1,2);
constexpr CGCell CGc6 =mkcell(0,2,0), CGc7 =mkcell(0,2,1), CGc8 =mkcell(0,2,2);
constexpr CGCell CGc9 =mkcell(1,0,0), CGc10=mkcell(1,0,1), CGc11=mkcell(1,0,2);
constexpr CGCell CGc12=mkcell(1,1,0), CGc13=mkcell(1,1,1), CGc14=mkcell(1,1,2);
constexpr CGCell CGc15=mkcell(1,2,0), CGc16=mkcell(1,2,1), CGc17=mkcell(1,2,2);
constexpr CGCell CGc18=mkcell(2,0,0), CGc19=mkcell(2,0,1), CGc20=mkcell(2,0,2);
constexpr CGCell CGc21=mkcell(2,1,0), CGc22=mkcell(2,1,1), CGc23=mkcell(2,1,2);
constexpr CGCell CGc24=mkcell(2,2,0), CGc25=mkcell(2,2,1), CGc26=mkcell(2,2,2);
__constant__ CGCell g_cg[27] = {
  CGc0,CGc1,CGc2,CGc3,CGc4,CGc5,CGc6,CGc7,CGc8,
  CGc9,CGc10,CGc11,CGc12,CGc13,CGc14,CGc15,CGc16,CGc17,
  CGc18,CGc19,CGc20,CGc21,CGc22,CGc23,CGc24,CGc25,CGc26};

// ---------------------------------------------------------------------------
// Compile-time layer specs (path enumeration is input-independent)
// ---------------------------------------------------------------------------
#define MAXP 32
struct LayerSpec {
  int np, zc, wn, nc;
  int x_off[MAXP], m1[MAXP], d1[MAXP], sh_off[MAXP], d2[MAXP], d3[MAXP],
      m3[MAXP], woff[MAXP], out_sl[MAXP], cg_idx[MAXP], zbase[MAXP], cell[MAXP];
  float alpha[MAXP];
  int cellcg[16];
};
constexpr LayerSpec mkspec(int li){
  LayerSpec S{};
  const int IRH[6][3]={{32,0,1},{32,0,-1},{8,1,1},{8,1,-1},{4,2,1},{4,2,-1}};
  const int IRS[1][3]={{32,0,1}};
  const int SH2[3][2]={{0,1},{1,-1},{2,1}};
  const int (*irin)[3]  = (li==0)? IRS: IRH; int nin =(li==0)?1:6;
  const int (*irout)[3] = (li==3)? IRS: IRH; int nout=(li==3)?1:6;
  int si_in[6]={}, si_out[6]={};
  { int o=0; for(int i=0;i<nin;i++){ si_in[i]=o;  o+=irin[i][0]*(2*irin[i][1]+1);} }
  { int o=0; for(int i=0;i<nout;i++){ si_out[i]=o; o+=irout[i][0]*(2*irout[i][1]+1);} }
  int fan[6]={};
  int i3a[MAXP]={};
  int np=0, woff=0, zb=0, nc=0;
  for(int i1=0;i1<nin;i1++){
    int m1=irin[i1][0], l1=irin[i1][1], p1=irin[i1][2];
    for(int s=0;s<3;s++){
      int l2=SH2[s][0], p2=SH2[s][1];
      for(int i3=0;i3<nout;i3++){
        int m3=irout[i3][0], l3=irout[i3][1], p3=irout[i3][2];
        int lo = l1>l2? l1-l2 : l2-l1;
        if(p1*p2==p3 && l3>=lo && l3<=l1+l2){
          S.x_off[np]=si_in[i1]; S.m1[np]=m1; S.d1[np]=2*l1+1;
          S.sh_off[np]=l2*l2; S.d2[np]=2*l2+1; S.d3[np]=2*l3+1;
          S.m3[np]=m3; S.woff[np]=woff; S.out_sl[np]=si_out[i3];
          S.cg_idx[np]=l1*9+l2*3+l3; S.zbase[np]=zb;
          int ci=-1;
          for(int c=0;c<nc;c++) if(S.cellcg[c]==S.cg_idx[np]) ci=c;
          if(ci<0){ S.cellcg[nc]=S.cg_idx[np]; ci=nc++; }
          S.cell[np]=ci; i3a[np]=i3;
          np++;
          fan[i3]+=m1; woff+=m1*m3; zb+=m1*(2*l3+1);
        }
      }
    }
  }
  for(int p=0;p<np;p++)
    S.alpha[p]=(float)csqrt((double)(2*((S.d3[p]-1)/2)+1)/(double)fan[i3a[p]]);
  S.np=np; S.zc=zb; S.wn=woff; S.nc=nc;
  return S;
}
constexpr LayerSpec LS0=mkspec(0), LS1=mkspec(1), LS2=mkspec(2), LS3=mkspec(3);
__constant__ LayerSpec g_spec[4]={LS0,LS1,LS2,LS3};

// ---------------------------------------------------------------------------
// Table builder: one block per layer, fully parallel (specs in __constant__)
// ---------------------------------------------------------------------------
__global__ __launch_bounds__(256) void build_tables_kernel(
    unsigned* __restrict__ slot_tab, unsigned* __restrict__ cell_tab,
    int* __restrict__ seg_start, unsigned* __restrict__ seg_ent,
    int* __restrict__ perm, float* __restrict__ alpha_col){
  __shared__ int vals[256];
  __shared__ int part[256];
  int tid=threadIdx.x;
  int li=blockIdx.x;          // grid = 4 layers
  const LayerSpec& S=g_spec[li];
  int np=S.np, zc=S.zc, nc=S.nc, wn=S.wn;
  // cell_tab
  for(int c=tid;c<nc;c+=256){
    int cgi=S.cellcg[c];
    int l2=(cgi/3)%3;
    cell_tab[li*CELL_N+c]=(unsigned)cgi | ((unsigned)(l2*l2)<<8) | ((unsigned)(2*l2+1)<<12);
  }
  // slot_tab
  for(int s=tid;s<zc;s+=256){
    int p=0; while(p+1<np && S.zbase[p+1]<=s) p++;
    int rel=s-S.zbase[p];
    int k=rel/S.m1[p], u=rel-k*S.m1[p];
    slot_tab[li*SLOT_MAX+s]=(unsigned)(S.x_off[p]+u*S.d1[p]) | ((unsigned)k<<9) | ((unsigned)S.cell[p]<<12);
  }
  // perm + alpha per column
  int* pm=perm+li*WNP_MAX;
  float* ac=alpha_col+li*WNP_MAX;
  for(int j=tid;j<wn;j+=256){
    int p=0; while(p+1<np && S.woff[p+1]<=j) p++;
    int rel=j-S.woff[p];
    int v=rel/S.m1[p], u=rel%S.m1[p];
    pm[j]=S.woff[p]+u*S.m3[p]+v;
    ac[j]=S.alpha[p];
  }
  // stage B segments: per-out-dim path counts, scan, fill
  int Dout=(li==3)?32:152;
  for(int d=tid;d<Dout;d+=256){
    int cnt=0;
    for(int p=0;p<np;p++){
      int rel=d-S.out_sl[p];
      if(rel>=0 && rel<S.m3[p]*S.d3[p]) cnt++;
    }
    vals[d]=cnt;
  }
  __syncthreads();
  int v0=(tid<Dout)? vals[tid]:0;
  part[tid]=v0;
  __syncthreads();
  for(int ofs=1;ofs<256;ofs<<=1){
    int v=(tid>=ofs)? part[tid-ofs]:0;
    __syncthreads();
    part[tid]+=v;
    __syncthreads();
  }
  int* sst=seg_start+li*SEG_S_N;
  if(tid<Dout) sst[tid]=part[tid]-v0;
  if(tid==0) sst[Dout]=part[255];
  __syncthreads();
  unsigned* se=seg_ent+li*SEG_ENT_MAX;
  for(int d=tid;d<Dout;d+=256){
    int pos=sst[d];
    for(int p=0;p<np;p++){
      int rel=d-S.out_sl[p];
      if(rel>=0 && rel<S.m3[p]*S.d3[p]){
        int v=rel/S.d3[p], k=rel%S.d3[p];
        unsigned z0=(unsigned)(S.zbase[p]+k*S.m1[p]);
        unsigned w0=(unsigned)(S.woff[p]+v*S.m1[p]);
        unsigned code=(S.m1[p]==32)?2u:((S.m1[p]==8)?1u:0u);
        se[pos]= z0 | (w0<<11) | (code<<24);
        pos++;
      }
    }
  }
}

// ---------------------------------------------------------------------------
// Geometry / embedding
// ---------------------------------------------------------------------------
__global__ void geom_kernel(const float* __restrict__ pos, const int* __restrict__ ei,
                            int* __restrict__ src2, int* __restrict__ dst2,
                            float* __restrict__ sh, float* __restrict__ rbf,
                            int* __restrict__ counts){
  int e=blockIdx.x*256+threadIdx.x;
  if(e>=E2) return;
  int s,d;
  if(e<NEDG){ s=ei[e]; d=ei[NEDG+e]; }
  else { int j=e-NEDG; s=ei[NEDG+j]; d=ei[j]; }
  src2[e]=s; dst2[e]=d;
  atomicAdd(&counts[s],1);
  float vx=pos[s*3+0]-pos[d*3+0];
  float vy=pos[s*3+1]-pos[d*3+1];
  float vz=pos[s*3+2]-pos[d*3+2];
  float len=sqrtf(vx*vx+vy*vy+vz*vz);
  float inv=1.f/len;
  float x=vx*inv, y=vy*inv, z=vz*inv;
  const float s3=1.7320508075688772f, s15=3.872983346207417f, s5=2.23606797749979f;
  float* shp=sh+(size_t)e*9;
  shp[0]=1.f; shp[1]=s3*y; shp[2]=s3*z; shp[3]=s3*x;
  shp[4]=s15*x*y; shp[5]=s15*y*z; shp[6]=s5*0.5f*(3.f*z*z-1.f);
  shp[7]=s15*x*z; shp[8]=s15*0.5f*(x*x-y*y);
  float* rp=rbf+(size_t)e*16;
  const float invsig=1.6f;               // 1/0.625
  for(int k=0;k<16;k++){
    float t=(len-(10.0f/15.0f)*(float)k)*invsig;
    rp[k]=expf(-t*t);
  }
}

__global__ void invc_kernel(const int* __restrict__ counts, float* __restrict__ invc){
  int n=blockIdx.x*256+threadIdx.x;
  if(n>=NNODES) return;
  int c=counts[n]; if(c<1) c=1;
  invc[n]=1.f/(float)c;
}

__global__ void embed_kernel(const float* __restrict__ x, const float* __restrict__ W,
                             const float* __restrict__ b, float* __restrict__ h){
  int idx=blockIdx.x*256+threadIdx.x;     // 2048*32
  int n=idx>>5, j=idx&31;
  float acc=b[j];
  for(int k=0;k<64;k++) acc += x[n*64+k]*W[k*32+j];
  h[(size_t)n*HSTR+j]=acc;
}

// ---------------------------------------------------------------------------
// All-layer w2 cast + transpose + permute + alpha-fold (one dispatch)
// w2t_all layout: layer l at element offset cum[l]*256, row-major [wnp][256]
// ---------------------------------------------------------------------------
__global__ void cast_all_kernel(const float* __restrict__ w2_0, const float* __restrict__ w2_1,
                                const float* __restrict__ w2_2, const float* __restrict__ w2_3,
                                const int* __restrict__ perm, const float* __restrict__ alpha_col,
                                __hip_bfloat16* __restrict__ w2t_all){
  int idx=blockIdx.x*256+threadIdx.x;
  if(idx>=WNP_TOT*256) return;
  int jj=idx>>8, k=idx&255;
  int l, j0;
  if(jj<1408){ l=0; j0=0; }
  else if(jj<1408+4352){ l=1; j0=1408; }
  else if(jj<1408+4352+4352){ l=2; j0=1408+4352; }
  else { l=3; j0=1408+4352+4352; }
  int j=jj-j0;
  const float* w2 = (l==0)? w2_0 : (l==1)? w2_1 : (l==2)? w2_2 : w2_3;
  int wn=LD_WN[l];
  float v=0.f;
  if(j<wn){
    int pj=perm[l*WNP_MAX+j];
    v=w2[(size_t)k*wn+pj]*alpha_col[l*WNP_MAX+j];
  }
  w2t_all[idx]=__float2bfloat16(v);
}

// ---------------------------------------------------------------------------
// Edge MLP layer 1 (fp32 compute, bf16 output)
// ---------------------------------------------------------------------------
__global__ __launch_bounds__(256) void mlp1_kernel(
    const float* __restrict__ h, const float* __restrict__ rbf,
    const int* __restrict__ src2, const int* __restrict__ dst2,
    const float* __restrict__ w1, const float* __restrict__ b1,
    __hip_bfloat16* __restrict__ hidden, int e_start){
  __shared__ float ef[16][80];
  int tid=threadIdx.x;
  int e0=e_start+blockIdx.x*16;
  for(int t=tid;t<16*80;t+=256){
    int el=t/80, k=t-el*80; int ge=e0+el;
    float v;
    if(k<16)      v=rbf[(size_t)ge*16+k];
    else if(k<48) v=h[(size_t)src2[ge]*HSTR+(k-16)];
    else          v=h[(size_t)dst2[ge]*HSTR+(k-48)];
    ef[el][k]=v;
  }
  __syncthreads();
  float acc[16];
  float bv=b1[tid];
  #pragma unroll
  for(int e=0;e<16;e++) acc[e]=bv;
  for(int k=0;k<80;k++){
    float wv=w1[k*256+tid];
    #pragma unroll
    for(int e=0;e<16;e++) acc[e]+=ef[e][k]*wv;
  }
  int le0=blockIdx.x*16;
  #pragma unroll
  for(int e=0;e<16;e++)
    hidden[(size_t)(le0+e)*256+tid]=__float2bfloat16(fmaxf(acc[e],0.f));
}

// ---------------------------------------------------------------------------
// Edge MLP layer 2: bf16 MFMA GEMM.  wbuf[M][N_pad](bf16) = hidden @ w2t^T (+bias)
// ---------------------------------------------------------------------------
__global__ __launch_bounds__(256) void mlp2_mfma_kernel(
    const __hip_bfloat16* __restrict__ hidden,   // [M][256] bf16 row-major
    const __hip_bfloat16* __restrict__ w2t,      // [N_pad][256] bf16 row-major (permuted, alpha-folded)
    const float* __restrict__ b2, const int* __restrict__ perm,
    const float* __restrict__ alpha_col,
    __hip_bfloat16* __restrict__ wbuf, int wn, int wn_pad){
  __shared__ __hip_bfloat16 As[128*32];
  __shared__ __hip_bfloat16 Bs[128*32];
  int tid=threadIdx.x;
  int lane=tid&63;
  int m0=blockIdx.x*128, n0=blockIdx.y*128;
  int mw=((tid>>6)&1)*64, nw=(tid>>7)*64;
  f32x4 acc[4][4];
  #pragma unroll
  for(int i=0;i<4;i++)
    #pragma unroll
    for(int j=0;j<4;j++) acc[i][j]=(f32x4){0.f,0.f,0.f,0.f};

  int i0=tid*8, i1=tid*8+2048;               // two 8-elem chunks of the 4096-elem tile
  int ar0=i0>>5, ac0=i0&31, ar1=i1>>5, ac1=i1&31;
  const int q4=lane>>4, c16=lane&15;

  for(int k0=0;k0<256;k0+=32){
    __syncthreads();
    *(uint4*)&As[ar0*32+ac0] = *(const uint4*)&hidden[(size_t)(m0+ar0)*256 + k0 + ac0];
    *(uint4*)&As[ar1*32+ac1] = *(const uint4*)&hidden[(size_t)(m0+ar1)*256 + k0 + ac1];
    *(uint4*)&Bs[ar0*32+ac0] = *(const uint4*)&w2t[(size_t)(n0+ar0)*256 + k0 + ac0];
    *(uint4*)&Bs[ar1*32+ac1] = *(const uint4*)&w2t[(size_t)(n0+ar1)*256 + k0 + ac1];
    __syncthreads();
    bf16x8 af[4], bfr[4];
    #pragma unroll
    for(int mi=0;mi<4;mi++) af[mi]=*(bf16x8*)&As[(mw+mi*16+c16)*32 + q4*8];
    #pragma unroll
    for(int ni=0;ni<4;ni++) bfr[ni]=*(bf16x8*)&Bs[(nw+ni*16+c16)*32 + q4*8];
    #pragma unroll
    for(int mi=0;mi<4;mi++)
      #pragma unroll
      for(int ni=0;ni<4;ni++)
        acc[mi][ni]=__builtin_amdgcn_mfma_f32_16x16x32_bf16(af[mi],bfr[ni],acc[mi][ni],0,0,0);
  }
  #pragma unroll
  for(int ni=0;ni<4;ni++){
    int col=n0+nw+ni*16+c16;
    float bias=(col<wn)? b2[perm[col]]*alpha_col[col]:0.f;
    #pragma unroll
    for(int mi=0;mi<4;mi++){
      int row=m0+mw+mi*16+q4*4;
      #pragma unroll
      for(int rr=0;rr<4;rr++)
        wbuf[(size_t)(row+rr)*wn_pad+col]=__float2bfloat16(acc[mi][ni][rr]+bias);
    }
  }
}

// ---------------------------------------------------------------------------
// Tensor-product messages, T-factored stage A (pipelined slot loads);
// stage B: prefetched seg_ent + 2-way unrolled segment loop (intra-lane MLP).
// bf16 zsm; accumulates into upd[src] via fp32 atomics.
// ---------------------------------------------------------------------------
__device__ inline void wave_sync(){
  __builtin_amdgcn_s_waitcnt(0);
  __builtin_amdgcn_wave_barrier();
}

__device__ inline float dot4z(const __hip_bfloat16* zp, const __hip_bfloat16* wp){
  uint2 zv=*(const uint2*)zp;          // 8B, aligned: z0 % 4 == 0
  uint2 wv=*(const uint2*)wp;
  const __hip_bfloat16* zl=(const __hip_bfloat16*)&zv;
  const __hip_bfloat16* wl=(const __hip_bfloat16*)&wv;
  float s=0.f;
  #pragma unroll
  for(int q=0;q<4;q++) s+=__bfloat162float(zl[q])*__bfloat162float(wl[q]);
  return s;
}
__device__ inline float dot8z(const __hip_bfloat16* zp, const __hip_bfloat16* wp){
  return dot4z(zp,wp)+dot4z(zp+4,wp+4);
}

__device__ inline float seg_dot(unsigned sg, const __hip_bfloat16* zbase,
                                const __hip_bfloat16* wrow){
  int z0=sg&2047, w0=(sg>>11)&8191, code=sg>>24;
  const __hip_bfloat16* zp=zbase+z0;
  const __hip_bfloat16* wp=wrow+w0;
  float s;
  if(code==2){
    s=0.f;
    #pragma unroll
    for(int t=0;t<4;t++) s+=dot8z(zp+t*8,wp+t*8);
  } else if(code==1){
    s=dot8z(zp,wp);
  } else {
    s=dot4z(zp,wp);
  }
  return s;
}

__global__ __launch_bounds__(256) void tp4_kernel(
    const float* __restrict__ h, const float* __restrict__ sh,
    const __hip_bfloat16* __restrict__ wbuf,
    const int* __restrict__ src2, const int* __restrict__ dst2,
    const unsigned* __restrict__ slot_tab, const unsigned* __restrict__ cell_tab,
    const int* __restrict__ seg_start, const unsigned* __restrict__ seg_ent,
    float* __restrict__ upd, int e_start, int Din, int Dout, int wstride,
    int zc, int nc){
  __shared__ float xrow[4][160];
  __shared__ float shs[4][12];
  __shared__ __hip_bfloat16 zsm[4][1088];
  __shared__ float Tw[4][376];        // [cell][k][i] stride 25, <=15 cells
  int tid=threadIdx.x, w=tid>>6, lane=tid&63;
  int le=blockIdx.x*4+w, ge=e_start+le;
  int dn=dst2[ge];
  int sn=src2[ge];
  for(int i=lane;i<Din;i+=64) xrow[w][i]=h[(size_t)dn*HSTR+i];
  for(int i=Din+lane;i<160;i+=64) xrow[w][i]=0.f;
  if(lane<9) shs[w][lane]=sh[(size_t)ge*9+lane];
  wave_sync();
  // T[cell][k][i] = sum_j cg[i,j,k]*sh[sh_off+j]
  float* T=&Tw[w][0];
  for(int t=lane;t<nc*25;t+=64){
    int c=t/25, r=t-c*25, k=r/5, i=r-k*5;
    unsigned cm=cell_tab[c];
    int cgi=cm&255, sho=(cm>>8)&15, d2=(cm>>12)&7;
    const float* cgp=g_cg[cgi].v + i*25 + k;
    float s=0.f;
    for(int j=0;j<d2;j++) s+=cgp[j*5]*shs[w][sho+j];
    T[t]=s;
  }
  wave_sync();
  // stage A: static 5-term dot per slot (bf16 store), slot_tab prefetched
  const float* xr=&xrow[w][0];
  unsigned st_next = slot_tab[lane];               // zc >= 64 always
  for(int s=lane;s<zc;s+=64){
    unsigned st=st_next;
    int s2=s+64;
    if(s2<zc) st_next=slot_tab[s2];
    int xb=st&511, k=(st>>9)&7, c=st>>12;
    const float* Tp=&T[c*25+k*5];
    float v=xr[xb]*Tp[0]+xr[xb+1]*Tp[1]+xr[xb+2]*Tp[2]+xr[xb+3]*Tp[3]+xr[xb+4]*Tp[4];
    zsm[w][s]=__float2bfloat16(v);
  }
  wave_sync();
  // stage B: prefetch seg_ent per dim, 2-wide unroll with dual accumulators
  const __hip_bfloat16* wrow=wbuf+(size_t)le*wstride;
  const __hip_bfloat16* zbase=&zsm[w][0];
  float* urow=upd+(size_t)sn*Dout;
  for(int d=lane;d<Dout;d+=64){
    int s0=seg_start[d], s1=seg_start[d+1];
    int ns=s1-s0;
    unsigned sgs[8];
    int npre=ns>8?8:ns;
    #pragma unroll 8
    for(int i=0;i<npre;i++) sgs[i]=seg_ent[s0+i];   // independent, batched
    float a0=0.f, a1=0.f;
    int i=0;
    for(; i+1<npre; i+=2){
      a0+=seg_dot(sgs[i],   zbase, wrow);
      a1+=seg_dot(sgs[i+1], zbase, wrow);
    }
    if(i<npre) a0+=seg_dot(sgs[i], zbase, wrow);
    for(int j=8;j<ns;j++) a1+=seg_dot(seg_ent[s0+j], zbase, wrow);
    atomicAdd(&urow[d], a0+a1);
  }
}

// ---------------------------------------------------------------------------
// Equivariant batch norm (upd holds per-node SUMS; invc applies the mean)
// ---------------------------------------------------------------------------
__device__ inline int hidden_chan_of_dim(int d){
  if(d<64)  return d;
  if(d<88)  return 64+(d-64)/3;
  if(d<112) return 72+(d-88)/3;
  if(d<132) return 80+(d-112)/5;
  return 84+(d-132)/5;
}
__device__ inline void hidden_chan_params(int c, int& off, int& dk, int& l0){
  if(c<64){ off=c; dk=1; l0=1; }
  else if(c<72){ off=64+(c-64)*3; dk=3; l0=0; }
  else if(c<80){ off=88+(c-72)*3; dk=3; l0=0; }
  else if(c<84){ off=112+(c-80)*5; dk=5; l0=0; }
  else { off=132+(c-84)*5; dk=5; l0=0; }
}

__global__ void stats_kernel(const float* __restrict__ upd, const float* __restrict__ invc,
                             float* __restrict__ stats, int Dout, int scalar_out){
  int c=blockIdx.x, tid=threadIdx.x;
  int off,dk,l0;
  if(scalar_out){ off=c; dk=1; l0=1; }
  else hidden_chan_params(c,off,dk,l0);
  float s=0.f, s2=0.f;
  int total=NNODES*dk;
  for(int t=tid;t<total;t+=256){
    int n=t/dk, k=t-n*dk;
    float v=upd[(size_t)n*Dout+off+k]*invc[n];
    s+=v; s2+=v*v;
  }
  __shared__ float rs[256], rs2[256];
  rs[tid]=s; rs2[tid]=s2; __syncthreads();
  for(int o=128;o>0;o>>=1){
    if(tid<o){ rs[tid]+=rs[tid+o]; rs2[tid]+=rs2[tid+o]; }
    __syncthreads();
  }
  if(tid==0){
    float cnt=(float)total;
    float mean = l0? rs[0]/cnt : 0.f;
    float var = rs2[0]/cnt - mean*mean;
    stats[c*2]=mean;
    stats[c*2+1]=1.0f/sqrtf(var+1e-5f);
  }
}

// apply: reads upd, zeroes it in place for the next layer; for the final
// layer also zeroes the gout region (consumed by graph_kernel afterwards).
__global__ void apply_kernel(float* __restrict__ upd, const float* __restrict__ invc,
                             const float* __restrict__ stats,
                             const float* __restrict__ h_cur, float* __restrict__ h_next,
                             float* __restrict__ gout_zero,
                             int Dout, int res_dim, int scalar_out, int out_stride){
  int idx=blockIdx.x*256+threadIdx.x;
  if(idx>=NNODES*Dout) return;
  int n=idx/Dout, d=idx-n*Dout;
  int c = scalar_out? d : hidden_chan_of_dim(d);
  float uv=upd[idx];
  upd[idx]=0.f;                                     // re-zero for next layer
  float v=(uv*invc[n]-stats[2*c])*stats[2*c+1];
  float res=(d<res_dim)? h_cur[(size_t)n*HSTR+d] : 0.f;
  h_next[(size_t)n*out_stride+d]=v+res;
  if(gout_zero && idx<NGRAPH*32) gout_zero[idx]=0.f;
}

// ---------------------------------------------------------------------------
// Graph readout
// ---------------------------------------------------------------------------
__global__ void graph_kernel(const float* __restrict__ hfin, const int* __restrict__ batch,
                             float* __restrict__ gout){
  int idx=blockIdx.x*256+threadIdx.x;     // 2048*32
  int n=idx>>5, d=idx&31;
  atomicAdd(&gout[batch[n]*32+d], hfin[idx]);
}

// ---------------------------------------------------------------------------
// Launch
// ---------------------------------------------------------------------------
extern "C" void kernel_launch(void* const* d_in, const int* in_sizes, int n_in,
                              void* d_out, int out_size, void* d_ws, size_t ws_size,
                              hipStream_t stream){
  (void)in_sizes; (void)n_in; (void)out_size;
  const float* x    =(const float*)d_in[0];
  const float* pos  =(const float*)d_in[1];
  const int*   ei   =(const int*)d_in[2];
  const int*   batch=(const int*)d_in[3];
  const float* emb_w=(const float*)d_in[4];
  const float* emb_b=(const float*)d_in[5];
  const float *W1[4], *B1[4], *W2[4], *B2[4];
  for(int l=0;l<4;l++){
    W1[l]=(const float*)d_in[6+4*l];
    B1[l]=(const float*)d_in[7+4*l];
    W2[l]=(const float*)d_in[8+4*l];
    B2[l]=(const float*)d_in[9+4*l];
  }
  int ZC[4]={LS0.zc,LS1.zc,LS2.zc,LS3.zc};
  int NC[4]={LS0.nc,LS1.nc,LS2.nc,LS3.nc};
  const int W2TOFF[4]={0,1408,1408+4352,1408+4352+4352};

  char* base=(char*)d_ws;
  size_t off=0;
  auto alloc=[&](size_t bytes)->char*{
    off=(off+255)&~(size_t)255;
    char* p=base+off; off+=bytes; return p;
  };
  float*  h_a   =(float*)alloc((size_t)NNODES*HSTR*4);
  float*  h_b   =(float*)alloc((size_t)NNODES*HSTR*4);
  float*  shb   =(float*)alloc((size_t)E2*9*4);
  float*  rbfb  =(float*)alloc((size_t)E2*16*4);
  int*    src2  =(int*)  alloc((size_t)E2*4);
  int*    dst2  =(int*)  alloc((size_t)E2*4);
  int*    counts=(int*)  alloc((size_t)NNODES*4);
  float*  invc  =(float*)alloc((size_t)NNODES*4);
  float*  upd   =(float*)alloc((size_t)NNODES*HSTR*4);
  float*  stats =(float*)alloc(256*4);
  unsigned* slot_tab=(unsigned*)alloc((size_t)4*SLOT_MAX*4);
  unsigned* cell_tg =(unsigned*)alloc((size_t)4*CELL_N*4);
  int*      seg_s   =(int*)     alloc((size_t)4*SEG_S_N*4);
  unsigned* seg_e   =(unsigned*)alloc((size_t)4*SEG_ENT_MAX*4);
  int*      perm    =(int*)     alloc((size_t)4*WNP_MAX*4);
  float*    alpha_c =(float*)   alloc((size_t)4*WNP_MAX*4);
  __hip_bfloat16* w2t_all=(__hip_bfloat16*)alloc((size_t)WNP_TOT*256*2);

  // full-size wbuf, single producer->consumer pass per layer
  int E_CHUNK=E2;
  while(E_CHUNK>128){
    size_t need=off;
    need=(need+255)&~(size_t)255; need+=(size_t)E_CHUNK*256*2;
    need=(need+255)&~(size_t)255; need+=(size_t)E_CHUNK*WNP_MAX*2;
    if(need<=ws_size) break;
    E_CHUNK>>=1;
  }
  __hip_bfloat16* hidden=(__hip_bfloat16*)alloc((size_t)E_CHUNK*256*2);
  __hip_bfloat16* wbuf  =(__hip_bfloat16*)alloc((size_t)E_CHUNK*WNP_MAX*2);

  hipMemsetAsync(counts,0,(size_t)NNODES*4,stream);
  hipMemsetAsync(upd,0,(size_t)NNODES*HSTR*4,stream);   // layer 0; later layers re-zeroed by apply
  build_tables_kernel<<<4,256,0,stream>>>(slot_tab,cell_tg,seg_s,seg_e,perm,alpha_c);
  geom_kernel<<<E2/256,256,0,stream>>>(pos,ei,src2,dst2,shb,rbfb,counts);
  invc_kernel<<<NNODES/256,256,0,stream>>>(counts,invc);
  embed_kernel<<<(NNODES*32)/256,256,0,stream>>>(x,emb_w,emb_b,h_a);
  cast_all_kernel<<<(WNP_TOT*256)/256,256,0,stream>>>(W2[0],W2[1],W2[2],W2[3],perm,alpha_c,w2t_all);

  float* h_cur=h_a; float* h_nxt=h_b;
  for(int li=0;li<4;li++){
    int wn=LD_WN[li], wnp=LD_WNP[li], Din=LD_DIN[li], Dout=LD_DOUT[li];
    __hip_bfloat16* w2t=w2t_all+(size_t)W2TOFF[li]*256;
    for(int e0=0;e0<E2;e0+=E_CHUNK){
      mlp1_kernel<<<E_CHUNK/16,256,0,stream>>>(h_cur,rbfb,src2,dst2,W1[li],B1[li],hidden,e0);
      dim3 g2(E_CHUNK/128, wnp/128);
      mlp2_mfma_kernel<<<g2,256,0,stream>>>(hidden,w2t,B2[li],perm+li*WNP_MAX,
                                            alpha_c+li*WNP_MAX,wbuf,wn,wnp);
      tp4_kernel<<<E_CHUNK/4,256,0,stream>>>(h_cur,shb,wbuf,src2,dst2,
          slot_tab+li*SLOT_MAX, cell_tg+li*CELL_N,
          seg_s+li*SEG_S_N, seg_e+li*SEG_ENT_MAX,
          upd,e0,Din,Dout,wnp, ZC[li], NC[li]);
    }
    stats_kernel<<<LD_NCH[li],256,0,stream>>>(upd,invc,stats,Dout,li==3?1:0);
    int tot=NNODES*Dout;
    if(li<3)
      apply_kernel<<<(tot+255)/256,256,0,stream>>>(upd,invc,stats,h_cur,h_nxt,
                                                   (float*)nullptr,Dout,LD_RES[li],0,HSTR);
    else
      apply_kernel<<<(tot+255)/256,256,0,stream>>>(upd,invc,stats,h_cur,(float*)d_out,
                                                   (float*)d_out+(size_t)NNODES*32,
                                                   Dout,LD_RES[li],1,32);
    float* tmp=h_cur; h_cur=h_nxt; h_nxt=tmp;
  }

  float* gout=(float*)d_out + (size_t)NNODES*32;
  graph_kernel<<<(NNODES*32)/256,256,0,stream>>>((const float*)d_out,batch,gout);
}

// Round 16
// 716.486 us; speedup vs baseline: 1.0510x; 1.0510x over previous
//
#include <hip/hip_runtime.h>
#include <hip/hip_bf16.h>
#include <math.h>

// ---------------------------------------------------------------------------
// Problem constants
// ---------------------------------------------------------------------------
#define NNODES 2048
#define NEDG   8192
#define E2     16384
#define NGRAPH 8
#define HSTR   152   // h row stride (max hidden dim)

static const int LD_DIN[4]  = {32,152,152,152};
static const int LD_DOUT[4] = {152,152,152,32};
static const int LD_WN[4]   = {1408,4320,4320,1408};
static const int LD_WNP[4]  = {1408,4352,4352,1408};   // padded to 128
static const int LD_NCH[4]  = {88,88,88,32};
static const int LD_RES[4]  = {32,152,152,152};
#define WNP_MAX 4352
#define WNP_TOT (1408+4352+4352+1408)   // 11520

// table sizes (element counts per layer)
#define SLOT_MAX    1088   // u32 per layer (zc <= 1072)
#define CELL_N      20     // u32 per layer (nc <= 15)
#define SEG_S_N     164    // ints per layer (Dout+1 <= 153)
#define SEG_ENT_MAX 1024   // u32 per layer (<=720 used)

typedef short bf16x8 __attribute__((ext_vector_type(8)));
typedef float f32x4  __attribute__((ext_vector_type(4)));

// ---------------------------------------------------------------------------
// Compile-time CG table (constexpr port of reference _su2_cg / _q / _real_cg)
// ---------------------------------------------------------------------------
constexpr double cfact(int n){ double r=1.0; for(int i=2;i<=n;i++) r*=(double)i; return r; }
constexpr double csqrt(double x){
  if(x<=0.0) return 0.0;
  double g = x>1.0? x:1.0;
  for(int i=0;i<64;i++) g=0.5*(g+x/g);
  return g;
}
constexpr double csu2cg(int j1,int j2,int j3,int m1,int m2,int m3){
  if(m1+m2!=m3) return 0.0;
  double pref = csqrt((double)(2*j3+1)*cfact(j3+j1-j2)*cfact(j3-j1+j2)*cfact(j1+j2-j3)/cfact(j1+j2+j3+1));
  pref *= csqrt(cfact(j3+m3)*cfact(j3-m3)*cfact(j1-m1)*cfact(j1+m1)*cfact(j2-m2)*cfact(j2+m2));
  double s=0.0;
  for(int k=0;k<=j1+j2-j3;k++){
    if(j1-m1-k<0||j2+m2-k<0||j3-j2+m1+k<0||j3-j1-m2+k<0) continue;
    double t=1.0/(cfact(k)*cfact(j1+j2-j3-k)*cfact(j1-m1-k)*cfact(j2+m2-k)*cfact(j3-j2+m1+k)*cfact(j3-j1-m2+k));
    s += (k&1)? -t : t;
  }
  return pref*s;
}
struct QM { double r[25]; double i[25]; };
constexpr QM cqmat(int l){
  QM q{};
  const double inv2=0.7071067811865476;
  for(int m=-l;m<0;m++){
    int am=-m;
    q.r[(l+m)*5+(l+am)] = inv2;
    q.i[(l+m)*5+(l-am)] = -inv2;
  }
  q.r[l*5+l]=1.0;
  for(int m=1;m<=l;m++){
    double sgn=(m&1)? -1.0:1.0;
    q.r[(l+m)*5+(l+m)] = sgn*inv2;
    q.i[(l+m)*5+(l-m)] = sgn*inv2;
  }
  for(int rep=0;rep<l;rep++){   // multiply by (-i): (a+bi)*(-i) = b - a i
    for(int t=0;t<25;t++){ double a=q.r[t], b=q.i[t]; q.r[t]=b; q.i[t]=-a; }
  }
  return q;
}
struct CGCell { float v[125]; };
constexpr CGCell mkcell(int l1,int l2,int l3){
  CGCell out{};
  int lo = l1>l2? l1-l2 : l2-l1;
  if(l3<lo || l3>l1+l2) return out;
  QM q1=cqmat(l1), q2=cqmat(l2), q3=cqmat(l3);
  int n1=2*l1+1,n2=2*l2+1,n3=2*l3+1;
  double C[125]={};
  for(int a=0;a<n1;a++)for(int b=0;b<n2;b++)for(int c=0;c<n3;c++)
    C[a*25+b*5+c]=csu2cg(l1,l2,l3,a-l1,b-l2,c-l3);
  double wr[125]={}, wi[125]={};
  for(int i=0;i<n1;i++)for(int j=0;j<n2;j++)for(int k=0;k<n3;k++){
    double ar=0.0, ai=0.0;
    for(int a=0;a<n1;a++)for(int b=0;b<n2;b++){
      double p1r=q1.r[a*5+i], p1i=q1.i[a*5+i];
      double p2r=q2.r[b*5+j], p2i=q2.i[b*5+j];
      double pr=p1r*p2r-p1i*p2i, pi=p1r*p2i+p1i*p2r;
      for(int c=0;c<n3;c++){
        double cv=C[a*25+b*5+c]; if(cv==0.0) continue;
        double p3r=q3.r[c*5+k], p3i=-q3.i[c*5+k];   // conj
        ar += (pr*p3r-pi*p3i)*cv;
        ai += (pr*p3i+pi*p3r)*cv;
      }
    }
    wr[i*25+j*5+k]=ar; wi[i*25+j*5+k]=ai;
  }
  double sr=0.0, si=0.0;
  for(int t=0;t<125;t++){ sr+=wr[t]*wr[t]; si+=wi[t]*wi[t]; }
  double nr=csqrt(sr), ni=csqrt(si);
  bool use_re = nr>=ni;
  double nn = use_re? nr:ni;
  double inv = (nn>1e-300)? 1.0/nn : 0.0;
  for(int t=0;t<125;t++) out.v[t]=(float)((use_re? wr[t]:wi[t])*inv);
  return out;
}
constexpr CGCell CGc0 =mkcell(0,0,0), CGc1 =mkcell(0,0,1), CGc2 =mkcell(0,0,2);
constexpr CGCell CGc3 =mkcell(0,1,0), CGc4 =mkcell(0,1,1), CGc5 =mkcell(0,1,2);
constexpr CGCell CGc6 =mkcell(0,2,0), CGc7 =mkcell(0,2,1), CGc8 =mkcell(0,2,2);
constexpr CGCell CGc9 =mkcell(1,0,0), CGc10=mkcell(1,0,1), CGc11=mkcell(1,0,2);
constexpr CGCell CGc12=mkcell(1,1,0), CGc13=mkcell(1,1,1), CGc14=mkcell(1,1,2);
constexpr CGCell CGc15=mkcell(1,2,0), CGc16=mkcell(1,2,1), CGc17=mkcell(1,2,2);
constexpr CGCell CGc18=mkcell(2,0,0), CGc19=mkcell(2,0,1), CGc20=mkcell(2,0,2);
constexpr CGCell CGc21=mkcell(2,1,0), CGc22=mkcell(2,1,1), CGc23=mkcell(2,1,2);
constexpr CGCell CGc24=mkcell(2,2,0), CGc25=mkcell(2,2,1), CGc26=mkcell(2,2,2);
__constant__ CGCell g_cg[27] = {
  CGc0,CGc1,CGc2,CGc3,CGc4,CGc5,CGc6,CGc7,CGc8,
  CGc9,CGc10,CGc11,CGc12,CGc13,CGc14,CGc15,CGc16,CGc17,
  CGc18,CGc19,CGc20,CGc21,CGc22,CGc23,CGc24,CGc25,CGc26};

// ---------------------------------------------------------------------------
// Compile-time layer specs (path enumeration is input-independent)
// ---------------------------------------------------------------------------
#define MAXP 32
struct LayerSpec {
  int np, zc, wn, nc;
  int x_off[MAXP], m1[MAXP], d1[MAXP], sh_off[MAXP], d2[MAXP], d3[MAXP],
      m3[MAXP], woff[MAXP], out_sl[MAXP], cg_idx[MAXP], zbase[MAXP], cell[MAXP];
  float alpha[MAXP];
  int cellcg[16];
};
constexpr LayerSpec mkspec(int li){
  LayerSpec S{};
  const int IRH[6][3]={{32,0,1},{32,0,-1},{8,1,1},{8,1,-1},{4,2,1},{4,2,-1}};
  const int IRS[1][3]={{32,0,1}};
  const int SH2[3][2]={{0,1},{1,-1},{2,1}};
  const int (*irin)[3]  = (li==0)? IRS: IRH; int nin =(li==0)?1:6;
  const int (*irout)[3] = (li==3)? IRS: IRH; int nout=(li==3)?1:6;
  int si_in[6]={}, si_out[6]={};
  { int o=0; for(int i=0;i<nin;i++){ si_in[i]=o;  o+=irin[i][0]*(2*irin[i][1]+1);} }
  { int o=0; for(int i=0;i<nout;i++){ si_out[i]=o; o+=irout[i][0]*(2*irout[i][1]+1);} }
  int fan[6]={};
  int i3a[MAXP]={};
  int np=0, woff=0, zb=0, nc=0;
  for(int i1=0;i1<nin;i1++){
    int m1=irin[i1][0], l1=irin[i1][1], p1=irin[i1][2];
    for(int s=0;s<3;s++){
      int l2=SH2[s][0], p2=SH2[s][1];
      for(int i3=0;i3<nout;i3++){
        int m3=irout[i3][0], l3=irout[i3][1], p3=irout[i3][2];
        int lo = l1>l2? l1-l2 : l2-l1;
        if(p1*p2==p3 && l3>=lo && l3<=l1+l2){
          S.x_off[np]=si_in[i1]; S.m1[np]=m1; S.d1[np]=2*l1+1;
          S.sh_off[np]=l2*l2; S.d2[np]=2*l2+1; S.d3[np]=2*l3+1;
          S.m3[np]=m3; S.woff[np]=woff; S.out_sl[np]=si_out[i3];
          S.cg_idx[np]=l1*9+l2*3+l3; S.zbase[np]=zb;
          int ci=-1;
          for(int c=0;c<nc;c++) if(S.cellcg[c]==S.cg_idx[np]) ci=c;
          if(ci<0){ S.cellcg[nc]=S.cg_idx[np]; ci=nc++; }
          S.cell[np]=ci; i3a[np]=i3;
          np++;
          fan[i3]+=m1; woff+=m1*m3; zb+=m1*(2*l3+1);
        }
      }
    }
  }
  for(int p=0;p<np;p++)
    S.alpha[p]=(float)csqrt((double)(2*((S.d3[p]-1)/2)+1)/(double)fan[i3a[p]]);
  S.np=np; S.zc=zb; S.wn=woff; S.nc=nc;
  return S;
}
constexpr LayerSpec LS0=mkspec(0), LS1=mkspec(1), LS2=mkspec(2), LS3=mkspec(3);
__constant__ LayerSpec g_spec[4]={LS0,LS1,LS2,LS3};

// ---------------------------------------------------------------------------
// Table builder: one block per layer, fully parallel (specs in __constant__)
// ---------------------------------------------------------------------------
__global__ __launch_bounds__(256) void build_tables_kernel(
    unsigned* __restrict__ slot_tab, unsigned* __restrict__ cell_tab,
    int* __restrict__ seg_start, unsigned* __restrict__ seg_ent,
    int* __restrict__ perm, float* __restrict__ alpha_col){
  __shared__ int vals[256];
  __shared__ int part[256];
  int tid=threadIdx.x;
  int li=blockIdx.x;          // grid = 4 layers
  const LayerSpec& S=g_spec[li];
  int np=S.np, zc=S.zc, nc=S.nc, wn=S.wn;
  // cell_tab
  for(int c=tid;c<nc;c+=256){
    int cgi=S.cellcg[c];
    int l2=(cgi/3)%3;
    cell_tab[li*CELL_N+c]=(unsigned)cgi | ((unsigned)(l2*l2)<<8) | ((unsigned)(2*l2+1)<<12);
  }
  // slot_tab
  for(int s=tid;s<zc;s+=256){
    int p=0; while(p+1<np && S.zbase[p+1]<=s) p++;
    int rel=s-S.zbase[p];
    int k=rel/S.m1[p], u=rel-k*S.m1[p];
    slot_tab[li*SLOT_MAX+s]=(unsigned)(S.x_off[p]+u*S.d1[p]) | ((unsigned)k<<9) | ((unsigned)S.cell[p]<<12);
  }
  // perm + alpha per column
  int* pm=perm+li*WNP_MAX;
  float* ac=alpha_col+li*WNP_MAX;
  for(int j=tid;j<wn;j+=256){
    int p=0; while(p+1<np && S.woff[p+1]<=j) p++;
    int rel=j-S.woff[p];
    int v=rel/S.m1[p], u=rel%S.m1[p];
    pm[j]=S.woff[p]+u*S.m3[p]+v;
    ac[j]=S.alpha[p];
  }
  // stage B segments: per-out-dim path counts, scan, fill
  int Dout=(li==3)?32:152;
  for(int d=tid;d<Dout;d+=256){
    int cnt=0;
    for(int p=0;p<np;p++){
      int rel=d-S.out_sl[p];
      if(rel>=0 && rel<S.m3[p]*S.d3[p]) cnt++;
    }
    vals[d]=cnt;
  }
  __syncthreads();
  int v0=(tid<Dout)? vals[tid]:0;
  part[tid]=v0;
  __syncthreads();
  for(int ofs=1;ofs<256;ofs<<=1){
    int v=(tid>=ofs)? part[tid-ofs]:0;
    __syncthreads();
    part[tid]+=v;
    __syncthreads();
  }
  int* sst=seg_start+li*SEG_S_N;
  if(tid<Dout) sst[tid]=part[tid]-v0;
  if(tid==0) sst[Dout]=part[255];
  __syncthreads();
  unsigned* se=seg_ent+li*SEG_ENT_MAX;
  for(int d=tid;d<Dout;d+=256){
    int pos=sst[d];
    for(int p=0;p<np;p++){
      int rel=d-S.out_sl[p];
      if(rel>=0 && rel<S.m3[p]*S.d3[p]){
        int v=rel/S.d3[p], k=rel%S.d3[p];
        unsigned z0=(unsigned)(S.zbase[p]+k*S.m1[p]);
        unsigned w0=(unsigned)(S.woff[p]+v*S.m1[p]);
        unsigned code=(S.m1[p]==32)?2u:((S.m1[p]==8)?1u:0u);
        se[pos]= z0 | (w0<<11) | (code<<24);
        pos++;
      }
    }
  }
}

// ---------------------------------------------------------------------------
// Geometry / embedding
// ---------------------------------------------------------------------------
__global__ void geom_kernel(const float* __restrict__ pos, const int* __restrict__ ei,
                            int* __restrict__ src2, int* __restrict__ dst2,
                            float* __restrict__ sh, float* __restrict__ rbf,
                            int* __restrict__ counts){
  int e=blockIdx.x*256+threadIdx.x;
  if(e>=E2) return;
  int s,d;
  if(e<NEDG){ s=ei[e]; d=ei[NEDG+e]; }
  else { int j=e-NEDG; s=ei[NEDG+j]; d=ei[j]; }
  src2[e]=s; dst2[e]=d;
  atomicAdd(&counts[s],1);
  float vx=pos[s*3+0]-pos[d*3+0];
  float vy=pos[s*3+1]-pos[d*3+1];
  float vz=pos[s*3+2]-pos[d*3+2];
  float len=sqrtf(vx*vx+vy*vy+vz*vz);
  float inv=1.f/len;
  float x=vx*inv, y=vy*inv, z=vz*inv;
  const float s3=1.7320508075688772f, s15=3.872983346207417f, s5=2.23606797749979f;
  float* shp=sh+(size_t)e*9;
  shp[0]=1.f; shp[1]=s3*y; shp[2]=s3*z; shp[3]=s3*x;
  shp[4]=s15*x*y; shp[5]=s15*y*z; shp[6]=s5*0.5f*(3.f*z*z-1.f);
  shp[7]=s15*x*z; shp[8]=s15*0.5f*(x*x-y*y);
  float* rp=rbf+(size_t)e*16;
  const float invsig=1.6f;               // 1/0.625
  for(int k=0;k<16;k++){
    float t=(len-(10.0f/15.0f)*(float)k)*invsig;
    rp[k]=expf(-t*t);
  }
}

__global__ void invc_kernel(const int* __restrict__ counts, float* __restrict__ invc){
  int n=blockIdx.x*256+threadIdx.x;
  if(n>=NNODES) return;
  int c=counts[n]; if(c<1) c=1;
  invc[n]=1.f/(float)c;
}

__global__ void embed_kernel(const float* __restrict__ x, const float* __restrict__ W,
                             const float* __restrict__ b, float* __restrict__ h){
  int idx=blockIdx.x*256+threadIdx.x;     // 2048*32
  int n=idx>>5, j=idx&31;
  float acc=b[j];
  for(int k=0;k<64;k++) acc += x[n*64+k]*W[k*32+j];
  h[(size_t)n*HSTR+j]=acc;
}

// ---------------------------------------------------------------------------
// All-layer w2 cast + transpose + permute + alpha-fold (one dispatch)
// ---------------------------------------------------------------------------
__global__ void cast_all_kernel(const float* __restrict__ w2_0, const float* __restrict__ w2_1,
                                const float* __restrict__ w2_2, const float* __restrict__ w2_3,
                                const int* __restrict__ perm, const float* __restrict__ alpha_col,
                                __hip_bfloat16* __restrict__ w2t_all){
  int idx=blockIdx.x*256+threadIdx.x;
  if(idx>=WNP_TOT*256) return;
  int jj=idx>>8, k=idx&255;
  int l, j0;
  if(jj<1408){ l=0; j0=0; }
  else if(jj<1408+4352){ l=1; j0=1408; }
  else if(jj<1408+4352+4352){ l=2; j0=1408+4352; }
  else { l=3; j0=1408+4352+4352; }
  int j=jj-j0;
  const float* w2 = (l==0)? w2_0 : (l==1)? w2_1 : (l==2)? w2_2 : w2_3;
  int wn=LD_WN[l];
  float v=0.f;
  if(j<wn){
    int pj=perm[l*WNP_MAX+j];
    v=w2[(size_t)k*wn+pj]*alpha_col[l*WNP_MAX+j];
  }
  w2t_all[idx]=__float2bfloat16(v);
}

// ---------------------------------------------------------------------------
// Edge MLP layer 1 (fp32 compute, bf16 output)
// ---------------------------------------------------------------------------
__global__ __launch_bounds__(256) void mlp1_kernel(
    const float* __restrict__ h, const float* __restrict__ rbf,
    const int* __restrict__ src2, const int* __restrict__ dst2,
    const float* __restrict__ w1, const float* __restrict__ b1,
    __hip_bfloat16* __restrict__ hidden, int e_start){
  __shared__ float ef[16][80];
  int tid=threadIdx.x;
  int e0=e_start+blockIdx.x*16;
  for(int t=tid;t<16*80;t+=256){
    int el=t/80, k=t-el*80; int ge=e0+el;
    float v;
    if(k<16)      v=rbf[(size_t)ge*16+k];
    else if(k<48) v=h[(size_t)src2[ge]*HSTR+(k-16)];
    else          v=h[(size_t)dst2[ge]*HSTR+(k-48)];
    ef[el][k]=v;
  }
  __syncthreads();
  float acc[16];
  float bv=b1[tid];
  #pragma unroll
  for(int e=0;e<16;e++) acc[e]=bv;
  for(int k=0;k<80;k++){
    float wv=w1[k*256+tid];
    #pragma unroll
    for(int e=0;e<16;e++) acc[e]+=ef[e][k]*wv;
  }
  int le0=blockIdx.x*16;
  #pragma unroll
  for(int e=0;e<16;e++)
    hidden[(size_t)(le0+e)*256+tid]=__float2bfloat16(fmaxf(acc[e],0.f));
}

// ---------------------------------------------------------------------------
// Edge MLP layer 2: bf16 MFMA GEMM.  wbuf[M][N_pad](bf16) = hidden @ w2t^T (+bias)
// ---------------------------------------------------------------------------
__global__ __launch_bounds__(256) void mlp2_mfma_kernel(
    const __hip_bfloat16* __restrict__ hidden,   // [M][256] bf16 row-major
    const __hip_bfloat16* __restrict__ w2t,      // [N_pad][256] bf16 row-major (permuted, alpha-folded)
    const float* __restrict__ b2, const int* __restrict__ perm,
    const float* __restrict__ alpha_col,
    __hip_bfloat16* __restrict__ wbuf, int wn, int wn_pad){
  __shared__ __hip_bfloat16 As[128*32];
  __shared__ __hip_bfloat16 Bs[128*32];
  int tid=threadIdx.x;
  int lane=tid&63;
  int m0=blockIdx.x*128, n0=blockIdx.y*128;
  int mw=((tid>>6)&1)*64, nw=(tid>>7)*64;
  f32x4 acc[4][4];
  #pragma unroll
  for(int i=0;i<4;i++)
    #pragma unroll
    for(int j=0;j<4;j++) acc[i][j]=(f32x4){0.f,0.f,0.f,0.f};

  int i0=tid*8, i1=tid*8+2048;               // two 8-elem chunks of the 4096-elem tile
  int ar0=i0>>5, ac0=i0&31, ar1=i1>>5, ac1=i1&31;
  const int q4=lane>>4, c16=lane&15;

  for(int k0=0;k0<256;k0+=32){
    __syncthreads();
    *(uint4*)&As[ar0*32+ac0] = *(const uint4*)&hidden[(size_t)(m0+ar0)*256 + k0 + ac0];
    *(uint4*)&As[ar1*32+ac1] = *(const uint4*)&hidden[(size_t)(m0+ar1)*256 + k0 + ac1];
    *(uint4*)&Bs[ar0*32+ac0] = *(const uint4*)&w2t[(size_t)(n0+ar0)*256 + k0 + ac0];
    *(uint4*)&Bs[ar1*32+ac1] = *(const uint4*)&w2t[(size_t)(n0+ar1)*256 + k0 + ac1];
    __syncthreads();
    bf16x8 af[4], bfr[4];
    #pragma unroll
    for(int mi=0;mi<4;mi++) af[mi]=*(bf16x8*)&As[(mw+mi*16+c16)*32 + q4*8];
    #pragma unroll
    for(int ni=0;ni<4;ni++) bfr[ni]=*(bf16x8*)&Bs[(nw+ni*16+c16)*32 + q4*8];
    #pragma unroll
    for(int mi=0;mi<4;mi++)
      #pragma unroll
      for(int ni=0;ni<4;ni++)
        acc[mi][ni]=__builtin_amdgcn_mfma_f32_16x16x32_bf16(af[mi],bfr[ni],acc[mi][ni],0,0,0);
  }
  #pragma unroll
  for(int ni=0;ni<4;ni++){
    int col=n0+nw+ni*16+c16;
    float bias=(col<wn)? b2[perm[col]]*alpha_col[col]:0.f;
    #pragma unroll
    for(int mi=0;mi<4;mi++){
      int row=m0+mw+mi*16+q4*4;
      #pragma unroll
      for(int rr=0;rr<4;rr++)
        wbuf[(size_t)(row+rr)*wn_pad+col]=__float2bfloat16(acc[mi][ni][rr]+bias);
    }
  }
}

// ---------------------------------------------------------------------------
// Tensor-product messages, T-factored stage A; bf16 zsm (17.9 KB LDS, 56% occ);
// simple loops (R14 form — min VGPR); accumulates into upd[src] via atomics.
// ---------------------------------------------------------------------------
__device__ inline void wave_sync(){
  __builtin_amdgcn_s_waitcnt(0);
  __builtin_amdgcn_wave_barrier();
}

__device__ inline float dot4z(const __hip_bfloat16* zp, const __hip_bfloat16* wp){
  uint2 zv=*(const uint2*)zp;          // 8B, aligned: z0 % 4 == 0
  uint2 wv=*(const uint2*)wp;
  const __hip_bfloat16* zl=(const __hip_bfloat16*)&zv;
  const __hip_bfloat16* wl=(const __hip_bfloat16*)&wv;
  float s=0.f;
  #pragma unroll
  for(int q=0;q<4;q++) s+=__bfloat162float(zl[q])*__bfloat162float(wl[q]);
  return s;
}
__device__ inline float dot8z(const __hip_bfloat16* zp, const __hip_bfloat16* wp){
  return dot4z(zp,wp)+dot4z(zp+4,wp+4);
}

__global__ __launch_bounds__(256) void tp4_kernel(
    const float* __restrict__ h, const float* __restrict__ sh,
    const __hip_bfloat16* __restrict__ wbuf,
    const int* __restrict__ src2, const int* __restrict__ dst2,
    const unsigned* __restrict__ slot_tab, const unsigned* __restrict__ cell_tab,
    const int* __restrict__ seg_start, const unsigned* __restrict__ seg_ent,
    float* __restrict__ upd, int e_start, int Din, int Dout, int wstride,
    int zc, int nc){
  __shared__ float xrow[4][160];
  __shared__ float shs[4][12];
  __shared__ __hip_bfloat16 zsm[4][1088];
  __shared__ float Tw[4][376];        // [cell][k][i] stride 25, <=15 cells
  int tid=threadIdx.x, w=tid>>6, lane=tid&63;
  int le=blockIdx.x*4+w, ge=e_start+le;
  int dn=dst2[ge];
  int sn=src2[ge];
  for(int i=lane;i<Din;i+=64) xrow[w][i]=h[(size_t)dn*HSTR+i];
  for(int i=Din+lane;i<160;i+=64) xrow[w][i]=0.f;
  if(lane<9) shs[w][lane]=sh[(size_t)ge*9+lane];
  wave_sync();
  // T[cell][k][i] = sum_j cg[i,j,k]*sh[sh_off+j]
  float* T=&Tw[w][0];
  for(int t=lane;t<nc*25;t+=64){
    int c=t/25, r=t-c*25, k=r/5, i=r-k*5;
    unsigned cm=cell_tab[c];
    int cgi=cm&255, sho=(cm>>8)&15, d2=(cm>>12)&7;
    const float* cgp=g_cg[cgi].v + i*25 + k;
    float s=0.f;
    for(int j=0;j<d2;j++) s+=cgp[j*5]*shs[w][sho+j];
    T[t]=s;
  }
  wave_sync();
  // stage A: static 5-term dot per slot (bf16 store)
  const float* xr=&xrow[w][0];
  for(int s=lane;s<zc;s+=64){
    unsigned st=slot_tab[s];
    int xb=st&511, k=(st>>9)&7, c=st>>12;
    const float* Tp=&T[c*25+k*5];
    float v=xr[xb]*Tp[0]+xr[xb+1]*Tp[1]+xr[xb+2]*Tp[2]+xr[xb+3]*Tp[3]+xr[xb+4]*Tp[4];
    zsm[w][s]=__float2bfloat16(v);
  }
  wave_sync();
  // stage B: segment dots (bf16 z x bf16 w), accumulate into upd[src]
  const __hip_bfloat16* wrow=wbuf+(size_t)le*wstride;
  const __hip_bfloat16* zbase=&zsm[w][0];
  float* urow=upd+(size_t)sn*Dout;
  for(int d=lane;d<Dout;d+=64){
    int s0=seg_start[d], s1=seg_start[d+1];
    float acc=0.f;
    for(int s=s0;s<s1;s++){
      unsigned sg=seg_ent[s];
      int z0=sg&2047, w0=(sg>>11)&8191, code=sg>>24;
      const __hip_bfloat16* zp=zbase+z0;
      const __hip_bfloat16* wp=wrow+w0;
      if(code==2){
        #pragma unroll
        for(int t=0;t<4;t++) acc+=dot8z(zp+t*8,wp+t*8);
      } else if(code==1){
        acc+=dot8z(zp,wp);
      } else {
        acc+=dot4z(zp,wp);
      }
    }
    atomicAdd(&urow[d], acc);
  }
}

// ---------------------------------------------------------------------------
// Equivariant batch norm (upd holds per-node SUMS; invc applies the mean)
// ---------------------------------------------------------------------------
__device__ inline int hidden_chan_of_dim(int d){
  if(d<64)  return d;
  if(d<88)  return 64+(d-64)/3;
  if(d<112) return 72+(d-88)/3;
  if(d<132) return 80+(d-112)/5;
  return 84+(d-132)/5;
}
__device__ inline void hidden_chan_params(int c, int& off, int& dk, int& l0){
  if(c<64){ off=c; dk=1; l0=1; }
  else if(c<72){ off=64+(c-64)*3; dk=3; l0=0; }
  else if(c<80){ off=88+(c-72)*3; dk=3; l0=0; }
  else if(c<84){ off=112+(c-80)*5; dk=5; l0=0; }
  else { off=132+(c-84)*5; dk=5; l0=0; }
}

__global__ void stats_kernel(const float* __restrict__ upd, const float* __restrict__ invc,
                             float* __restrict__ stats, int Dout, int scalar_out){
  int c=blockIdx.x, tid=threadIdx.x;
  int off,dk,l0;
  if(scalar_out){ off=c; dk=1; l0=1; }
  else hidden_chan_params(c,off,dk,l0);
  float s=0.f, s2=0.f;
  int total=NNODES*dk;
  for(int t=tid;t<total;t+=256){
    int n=t/dk, k=t-n*dk;
    float v=upd[(size_t)n*Dout+off+k]*invc[n];
    s+=v; s2+=v*v;
  }
  __shared__ float rs[256], rs2[256];
  rs[tid]=s; rs2[tid]=s2; __syncthreads();
  for(int o=128;o>0;o>>=1){
    if(tid<o){ rs[tid]+=rs[tid+o]; rs2[tid]+=rs2[tid+o]; }
    __syncthreads();
  }
  if(tid==0){
    float cnt=(float)total;
    float mean = l0? rs[0]/cnt : 0.f;
    float var = rs2[0]/cnt - mean*mean;
    stats[c*2]=mean;
    stats[c*2+1]=1.0f/sqrtf(var+1e-5f);
  }
}

// apply: reads upd, zeroes it in place for the next layer; for the final
// layer also zeroes the gout region (consumed by graph_kernel afterwards).
__global__ void apply_kernel(float* __restrict__ upd, const float* __restrict__ invc,
                             const float* __restrict__ stats,
                             const float* __restrict__ h_cur, float* __restrict__ h_next,
                             float* __restrict__ gout_zero,
                             int Dout, int res_dim, int scalar_out, int out_stride){
  int idx=blockIdx.x*256+threadIdx.x;
  if(idx>=NNODES*Dout) return;
  int n=idx/Dout, d=idx-n*Dout;
  int c = scalar_out? d : hidden_chan_of_dim(d);
  float uv=upd[idx];
  upd[idx]=0.f;                                     // re-zero for next layer
  float v=(uv*invc[n]-stats[2*c])*stats[2*c+1];
  float res=(d<res_dim)? h_cur[(size_t)n*HSTR+d] : 0.f;
  h_next[(size_t)n*out_stride+d]=v+res;
  if(gout_zero && idx<NGRAPH*32) gout_zero[idx]=0.f;
}

// ---------------------------------------------------------------------------
// Graph readout
// ---------------------------------------------------------------------------
__global__ void graph_kernel(const float* __restrict__ hfin, const int* __restrict__ batch,
                             float* __restrict__ gout){
  int idx=blockIdx.x*256+threadIdx.x;     // 2048*32
  int n=idx>>5, d=idx&31;
  atomicAdd(&gout[batch[n]*32+d], hfin[idx]);
}

// ---------------------------------------------------------------------------
// Launch
// ---------------------------------------------------------------------------
extern "C" void kernel_launch(void* const* d_in, const int* in_sizes, int n_in,
                              void* d_out, int out_size, void* d_ws, size_t ws_size,
                              hipStream_t stream){
  (void)in_sizes; (void)n_in; (void)out_size;
  const float* x    =(const float*)d_in[0];
  const float* pos  =(const float*)d_in[1];
  const int*   ei   =(const int*)d_in[2];
  const int*   batch=(const int*)d_in[3];
  const float* emb_w=(const float*)d_in[4];
  const float* emb_b=(const float*)d_in[5];
  const float *W1[4], *B1[4], *W2[4], *B2[4];
  for(int l=0;l<4;l++){
    W1[l]=(const float*)d_in[6+4*l];
    B1[l]=(const float*)d_in[7+4*l];
    W2[l]=(const float*)d_in[8+4*l];
    B2[l]=(const float*)d_in[9+4*l];
  }
  int ZC[4]={LS0.zc,LS1.zc,LS2.zc,LS3.zc};
  int NC[4]={LS0.nc,LS1.nc,LS2.nc,LS3.nc};
  const int W2TOFF[4]={0,1408,1408+4352,1408+4352+4352};

  char* base=(char*)d_ws;
  size_t off=0;
  auto alloc=[&](size_t bytes)->char*{
    off=(off+255)&~(size_t)255;
    char* p=base+off; off+=bytes; return p;
  };
  float*  h_a   =(float*)alloc((size_t)NNODES*HSTR*4);
  float*  h_b   =(float*)alloc((size_t)NNODES*HSTR*4);
  float*  shb   =(float*)alloc((size_t)E2*9*4);
  float*  rbfb  =(float*)alloc((size_t)E2*16*4);
  int*    src2  =(int*)  alloc((size_t)E2*4);
  int*    dst2  =(int*)  alloc((size_t)E2*4);
  int*    counts=(int*)  alloc((size_t)NNODES*4);
  float*  invc  =(float*)alloc((size_t)NNODES*4);
  float*  upd   =(float*)alloc((size_t)NNODES*HSTR*4);
  float*  stats =(float*)alloc(256*4);
  unsigned* slot_tab=(unsigned*)alloc((size_t)4*SLOT_MAX*4);
  unsigned* cell_tg =(unsigned*)alloc((size_t)4*CELL_N*4);
  int*      seg_s   =(int*)     alloc((size_t)4*SEG_S_N*4);
  unsigned* seg_e   =(unsigned*)alloc((size_t)4*SEG_ENT_MAX*4);
  int*      perm    =(int*)     alloc((size_t)4*WNP_MAX*4);
  float*    alpha_c =(float*)   alloc((size_t)4*WNP_MAX*4);
  __hip_bfloat16* w2t_all=(__hip_bfloat16*)alloc((size_t)WNP_TOT*256*2);

  // full-size wbuf, single producer->consumer pass per layer
  int E_CHUNK=E2;
  while(E_CHUNK>128){
    size_t need=off;
    need=(need+255)&~(size_t)255; need+=(size_t)E_CHUNK*256*2;
    need=(need+255)&~(size_t)255; need+=(size_t)E_CHUNK*WNP_MAX*2;
    if(need<=ws_size) break;
    E_CHUNK>>=1;
  }
  __hip_bfloat16* hidden=(__hip_bfloat16*)alloc((size_t)E_CHUNK*256*2);
  __hip_bfloat16* wbuf  =(__hip_bfloat16*)alloc((size_t)E_CHUNK*WNP_MAX*2);

  hipMemsetAsync(counts,0,(size_t)NNODES*4,stream);
  hipMemsetAsync(upd,0,(size_t)NNODES*HSTR*4,stream);   // layer 0; later layers re-zeroed by apply
  build_tables_kernel<<<4,256,0,stream>>>(slot_tab,cell_tg,seg_s,seg_e,perm,alpha_c);
  geom_kernel<<<E2/256,256,0,stream>>>(pos,ei,src2,dst2,shb,rbfb,counts);
  invc_kernel<<<NNODES/256,256,0,stream>>>(counts,invc);
  embed_kernel<<<(NNODES*32)/256,256,0,stream>>>(x,emb_w,emb_b,h_a);
  cast_all_kernel<<<(WNP_TOT*256)/256,256,0,stream>>>(W2[0],W2[1],W2[2],W2[3],perm,alpha_c,w2t_all);

  float* h_cur=h_a; float* h_nxt=h_b;
  for(int li=0;li<4;li++){
    int wn=LD_WN[li], wnp=LD_WNP[li], Din=LD_DIN[li], Dout=LD_DOUT[li];
    __hip_bfloat16* w2t=w2t_all+(size_t)W2TOFF[li]*256;
    for(int e0=0;e0<E2;e0+=E_CHUNK){
      mlp1_kernel<<<E_CHUNK/16,256,0,stream>>>(h_cur,rbfb,src2,dst2,W1[li],B1[li],hidden,e0);
      dim3 g2(E_CHUNK/128, wnp/128);
      mlp2_mfma_kernel<<<g2,256,0,stream>>>(hidden,w2t,B2[li],perm+li*WNP_MAX,
                                            alpha_c+li*WNP_MAX,wbuf,wn,wnp);
      tp4_kernel<<<E_CHUNK/4,256,0,stream>>>(h_cur,shb,wbuf,src2,dst2,
          slot_tab+li*SLOT_MAX, cell_tg+li*CELL_N,
          seg_s+li*SEG_S_N, seg_e+li*SEG_ENT_MAX,
          upd,e0,Din,Dout,wnp, ZC[li], NC[li]);
    }
    stats_kernel<<<LD_NCH[li],256,0,stream>>>(upd,invc,stats,Dout,li==3?1:0);
    int tot=NNODES*Dout;
    if(li<3)
      apply_kernel<<<(tot+255)/256,256,0,stream>>>(upd,invc,stats,h_cur,h_nxt,
                                                   (float*)nullptr,Dout,LD_RES[li],0,HSTR);
    else
      apply_kernel<<<(tot+255)/256,256,0,stream>>>(upd,invc,stats,h_cur,(float*)d_out,
                                                   (float*)d_out+(size_t)NNODES*32,
                                                   Dout,LD_RES[li],1,32);
    float* tmp=h_cur; h_cur=h_nxt; h_nxt=tmp;
  }

  float* gout=(float*)d_out + (size_t)NNODES*32;
  graph_kernel<<<(NNODES*32)/256,256,0,stream>>>((const float*)d_out,batch,gout);
}